// Round 1
// baseline (647.650 us; speedup 1.0000x reference)
//
#include <hip/hip_runtime.h>

#define NN 50000
#define MP 50048   // 391 * 128
#define DD 512
#define EE 800000

typedef unsigned short u16;
typedef __attribute__((ext_vector_type(4))) float f32x4;
typedef __attribute__((ext_vector_type(8))) __bf16 bf16x8;
typedef __attribute__((ext_vector_type(8))) short s16x8;
typedef __attribute__((ext_vector_type(4))) short s16x4;

typedef __attribute__((address_space(1))) const void GVoid;
typedef __attribute__((address_space(3))) void LVoid;

__device__ __forceinline__ u16 f2bf(float f) {
  union { float f; unsigned u; } x; x.f = f;
  unsigned r = x.u + 0x7fffu + ((x.u >> 16) & 1u);   // RTNE
  return (u16)(r >> 16);
}
__device__ __forceinline__ float bf2f(u16 b) {
  union { unsigned u; float f; } x; x.u = ((unsigned)b) << 16;
  return x.f;
}

// ---------------- graph preprocessing ----------------

__global__ __launch_bounds__(256) void zero_cnt_k(int* cnt) {
  int i = blockIdx.x * 256 + threadIdx.x;
  if (i < NN) cnt[i] = 0;
}

__global__ __launch_bounds__(256) void count_k(const int* __restrict__ dst, int* __restrict__ cnt) {
  int e = blockIdx.x * 256 + threadIdx.x;
  if (e < EE) atomicAdd(&cnt[dst[e]], 1);
}

__global__ __launch_bounds__(256) void dinv_k(const int* __restrict__ cnt, float* __restrict__ dinv) {
  int i = blockIdx.x * 256 + threadIdx.x;
  if (i < NN) dinv[i] = rsqrtf((float)(cnt[i] + 1));   // +1 = self-loop
}

__global__ __launch_bounds__(1024) void scan_k(const int* __restrict__ cnt, int* __restrict__ rowp,
                                               int* __restrict__ cursor) {
  __shared__ int sums[1024];
  const int t = threadIdx.x;
  const int chunk = (NN + 1023) / 1024;      // 49
  const int beg = t * chunk;
  const int end = (beg + chunk < NN) ? (beg + chunk) : NN;
  int s = 0;
  for (int i = beg; i < end; ++i) s += cnt[i];
  sums[t] = s;
  __syncthreads();
  for (int off = 1; off < 1024; off <<= 1) {   // inclusive Hillis-Steele
    int v = sums[t];
    int u = (t >= off) ? sums[t - off] : 0;
    __syncthreads();
    sums[t] = v + u;
    __syncthreads();
  }
  int run = (t == 0) ? 0 : sums[t - 1];
  for (int i = beg; i < end; ++i) { rowp[i] = run; cursor[i] = run; run += cnt[i]; }
  if (t == 1023) rowp[NN] = run;               // chunks past NN are empty -> run == total
}

__global__ __launch_bounds__(256) void scatter_k(const int* __restrict__ src, const int* __restrict__ dst,
                                                 const float* __restrict__ dinv, int* __restrict__ cursor,
                                                 int* __restrict__ csr_s, float* __restrict__ csr_w) {
  int e = blockIdx.x * 256 + threadIdx.x;
  if (e >= EE) return;
  int d = dst[e], s = src[e];
  int pos = atomicAdd(&cursor[d], 1);
  csr_s[pos] = s;
  csr_w[pos] = dinv[s] * dinv[d];
}

// ---------------- dtype conversion ----------------

__global__ __launch_bounds__(256) void convert_x_k(const float* __restrict__ x, u16* __restrict__ xb) {
  size_t i = ((size_t)blockIdx.x * 256 + threadIdx.x) * 4;
  if (i >= (size_t)MP * DD) return;
  s16x4 v;
  if (i < (size_t)NN * DD) {
    f32x4 f = *(const f32x4*)(x + i);
    v = (s16x4){ (short)f2bf(f.x), (short)f2bf(f.y), (short)f2bf(f.z), (short)f2bf(f.w) };
  } else {
    v = (s16x4){ 0, 0, 0, 0 };                 // zero pad rows (M -> MP)
  }
  *(s16x4*)(xb + i) = v;
}

__global__ __launch_bounds__(256) void convert_wt_k(const float* __restrict__ W, u16* __restrict__ WT, int ncols) {
  int idx = blockIdx.x * 256 + threadIdx.x;    // over ncols*512, WT is [ncols][512] = B^T
  if (idx >= 512 * ncols) return;
  int n = idx >> 9, k = idx & 511;
  WT[idx] = f2bf(W[(size_t)k * ncols + n]);
}

// ---------------- bf16 MFMA GEMM (m97 structure: 128x128 tile, 4 waves, BK=32) ----------------

template<int OUT_BF16>
__global__ __launch_bounds__(256) void gemm_k(const u16* __restrict__ A, const u16* __restrict__ BT,
                                              void* __restrict__ Cv, const float* __restrict__ bias,
                                              int M, int N) {
  __shared__ u16 As[128 * 32];
  __shared__ u16 Bs[128 * 32];
  const int ntn = N >> 7;
  const int bm = (int)blockIdx.x / ntn;
  const int bn = (int)blockIdx.x % ntn;
  const int t = threadIdx.x;
  const int lane = t & 63;
  const int wc = (t >> 6) & 1;
  const int wr = (t >> 7) & 1;
  f32x4 acc[4][4] = {};
  const int r0 = t >> 2;                        // staging row 0..63
  const int kc = (t & 3) * 8;                   // staging k-col
  const u16* Ab = A + (size_t)bm * 128 * DD + (size_t)r0 * DD + kc;
  const u16* Bb = BT + (size_t)bn * 128 * DD + (size_t)r0 * DD + kc;

  for (int kt = 0; kt < DD; kt += 32) {
    __builtin_amdgcn_global_load_lds((GVoid*)(Ab + kt),           (LVoid*)(&As[t * 8]),        16, 0, 0);
    __builtin_amdgcn_global_load_lds((GVoid*)(Ab + 64 * DD + kt), (LVoid*)(&As[2048 + t * 8]), 16, 0, 0);
    __builtin_amdgcn_global_load_lds((GVoid*)(Bb + kt),           (LVoid*)(&Bs[t * 8]),        16, 0, 0);
    __builtin_amdgcn_global_load_lds((GVoid*)(Bb + 64 * DD + kt), (LVoid*)(&Bs[2048 + t * 8]), 16, 0, 0);
    __syncthreads();                            // compiler drains vmcnt before barrier
    bf16x8 af[4], bv[4];
    #pragma unroll
    for (int m = 0; m < 4; ++m)
      af[m] = *(const bf16x8*)&As[(wr * 64 + m * 16 + (lane & 15)) * 32 + (lane >> 4) * 8];
    #pragma unroll
    for (int n = 0; n < 4; ++n)
      bv[n] = *(const bf16x8*)&Bs[(wc * 64 + n * 16 + (lane & 15)) * 32 + (lane >> 4) * 8];
    #pragma unroll
    for (int m = 0; m < 4; ++m) {
      #pragma unroll
      for (int n = 0; n < 4; ++n)
        acc[m][n] = __builtin_amdgcn_mfma_f32_16x16x32_bf16(af[m], bv[n], acc[m][n], 0, 0, 0);
    }
    __syncthreads();                            // protect LDS before next stage
  }

  // C layout (m89-verified): col = lane&15, row = (lane>>4)*4 + reg
  const int rb = bm * 128 + wr * 64 + ((lane >> 4) * 4);
  const int cb = bn * 128 + wc * 64 + (lane & 15);
  #pragma unroll
  for (int m = 0; m < 4; ++m) {
    #pragma unroll
    for (int r = 0; r < 4; ++r) {
      const int row = rb + m * 16 + r;
      if (row < M) {
        #pragma unroll
        for (int n = 0; n < 4; ++n) {
          const int col = cb + n * 16;
          float v = acc[m][n][r];
          if (bias) v += bias[col];
          if (OUT_BF16) ((u16*)Cv)[(size_t)row * N + col] = f2bf(v);
          else          ((float*)Cv)[(size_t)row * N + col] = v;
        }
      }
    }
  }
}

// ---------------- CSR aggregation: one wave per dst node, 8 dims/lane ----------------

__global__ __launch_bounds__(256) void aggregate_k(const u16* __restrict__ H, const int* __restrict__ rowp,
                                                   const int* __restrict__ csr_s, const float* __restrict__ csr_w,
                                                   const float* __restrict__ dinv, const float* __restrict__ bias,
                                                   u16* __restrict__ out) {
  const int wid = threadIdx.x >> 6;
  const int lane = threadIdx.x & 63;
  const int node = blockIdx.x * 4 + wid;        // grid = NN/4 exactly
  const int d0 = lane * 8;
  const int beg = rowp[node];
  const int end = rowp[node + 1];
  float acc[8] = {0.f, 0.f, 0.f, 0.f, 0.f, 0.f, 0.f, 0.f};
  for (int e = beg; e < end; ++e) {
    const int s = csr_s[e];
    const float w = csr_w[e];
    s16x8 v = *(const s16x8*)(H + (size_t)s * DD + d0);   // 64 lanes x 16B = full 1KB row
    #pragma unroll
    for (int j = 0; j < 8; ++j) acc[j] += bf2f((u16)v[j]) * w;
  }
  // self-loop: + h[node] * dinv[node]^2
  const float di = dinv[node];
  const float wsl = di * di;
  {
    s16x8 v = *(const s16x8*)(H + (size_t)node * DD + d0);
    #pragma unroll
    for (int j = 0; j < 8; ++j) acc[j] += bf2f((u16)v[j]) * wsl;
  }
  s16x8 o;
  #pragma unroll
  for (int j = 0; j < 8; ++j) {
    float r = acc[j] + bias[d0 + j];
    r = fmaxf(r, 0.f);                          // relu
    o[j] = (short)f2bf(r);
  }
  *(s16x8*)(out + (size_t)node * DD + d0) = o;
}

// ---------------- launch ----------------

extern "C" void kernel_launch(void* const* d_in, const int* in_sizes, int n_in,
                              void* d_out, int out_size, void* d_ws, size_t ws_size,
                              hipStream_t stream) {
  const float* x    = (const float*)d_in[0];
  const int*   ei   = (const int*)d_in[1];
  const float* W1   = (const float*)d_in[2];
  const float* b1   = (const float*)d_in[3];
  const float* W2   = (const float*)d_in[4];
  const float* b2   = (const float*)d_in[5];
  const float* Wout = (const float*)d_in[6];
  const float* bout = (const float*)d_in[7];
  float* out = (float*)d_out;
  (void)in_sizes; (void)n_in; (void)out_size; (void)ws_size;

  char* ws = (char*)d_ws;
  size_t off = 0;
  auto alloc = [&](size_t bytes) -> char* {
    char* p = ws + off;
    off = (off + bytes + 255) & ~(size_t)255;
    return p;
  };
  u16*   xb   = (u16*)alloc((size_t)MP * DD * 2);   // activations bf16, padded rows
  u16*   H    = (u16*)alloc((size_t)NN * DD * 2);   // GEMM output bf16
  u16*   W1T  = (u16*)alloc(512 * 512 * 2);
  u16*   W2T  = (u16*)alloc(512 * 512 * 2);
  u16*   WoT  = (u16*)alloc(256 * 512 * 2);
  int*   cnt  = (int*)alloc(NN * 4);
  float* dinv = (float*)alloc(NN * 4);
  int*   rowp = (int*)alloc((NN + 1) * 4);
  int*   cur  = (int*)alloc(NN * 4);
  int*   csrs = (int*)alloc((size_t)EE * 4);
  float* csrw = (float*)alloc((size_t)EE * 4);

  const int* srcp = ei;        // edge_index[0]
  const int* dstp = ei + EE;   // edge_index[1]

  zero_cnt_k<<<(NN + 255) / 256, 256, 0, stream>>>(cnt);
  count_k<<<(EE + 255) / 256, 256, 0, stream>>>(dstp, cnt);
  dinv_k<<<(NN + 255) / 256, 256, 0, stream>>>(cnt, dinv);
  scan_k<<<1, 1024, 0, stream>>>(cnt, rowp, cur);
  scatter_k<<<(EE + 255) / 256, 256, 0, stream>>>(srcp, dstp, dinv, cur, csrs, csrw);
  convert_x_k<<<(int)(((size_t)MP * DD / 4 + 255) / 256), 256, 0, stream>>>(x, xb);
  convert_wt_k<<<(512 * 512 + 255) / 256, 256, 0, stream>>>(W1, W1T, 512);
  convert_wt_k<<<(512 * 512 + 255) / 256, 256, 0, stream>>>(W2, W2T, 512);
  convert_wt_k<<<(512 * 256 + 255) / 256, 256, 0, stream>>>(Wout, WoT, 256);

  // layer 1: H = xb @ W1 ; xb = relu(agg(H) + b1)
  gemm_k<1><<<(MP / 128) * (512 / 128), 256, 0, stream>>>(xb, W1T, (void*)H, nullptr, NN, 512);
  aggregate_k<<<NN / 4, 256, 0, stream>>>(H, rowp, csrs, csrw, dinv, b1, xb);
  // layer 2
  gemm_k<1><<<(MP / 128) * (512 / 128), 256, 0, stream>>>(xb, W2T, (void*)H, nullptr, NN, 512);
  aggregate_k<<<NN / 4, 256, 0, stream>>>(H, rowp, csrs, csrw, dinv, b2, xb);
  // output layer: out = xb @ Wout + bout (f32, no relu, no aggregation)
  gemm_k<0><<<(MP / 128) * (256 / 128), 256, 0, stream>>>(xb, WoT, (void*)out, bout, NN, 256);
}

// Round 2
// 633.881 us; speedup vs baseline: 1.0217x; 1.0217x over previous
//
#include <hip/hip_runtime.h>

#define NN 50000
#define MP 50048   // 391 * 128
#define DD 512
#define EE 800000

typedef unsigned short u16;
typedef __attribute__((ext_vector_type(4))) float f32x4;
typedef __attribute__((ext_vector_type(8))) __bf16 bf16x8;
typedef __attribute__((ext_vector_type(8))) short s16x8;
typedef __attribute__((ext_vector_type(4))) short s16x4;

typedef __attribute__((address_space(1))) const void GVoid;
typedef __attribute__((address_space(3))) void LVoid;

__device__ __forceinline__ u16 f2bf(float f) {
  union { float f; unsigned u; } x; x.f = f;
  unsigned r = x.u + 0x7fffu + ((x.u >> 16) & 1u);   // RTNE
  return (u16)(r >> 16);
}
__device__ __forceinline__ float bf2f(u16 b) {
  union { unsigned u; float f; } x; x.u = ((unsigned)b) << 16;
  return x.f;
}

// ---------------- graph preprocessing ----------------
// Self-loops are materialized as real CSR edges: cnt starts at 1, scatter's
// last NN threads append (i -> i, dinv[i]^2).

__global__ __launch_bounds__(256) void init_cnt_k(int* cnt) {
  int i = blockIdx.x * 256 + threadIdx.x;
  if (i < NN) cnt[i] = 1;                      // self-loop pre-counted
}

__global__ __launch_bounds__(256) void count_k(const int* __restrict__ dst, int* __restrict__ cnt) {
  int e = blockIdx.x * 256 + threadIdx.x;
  if (e < EE) atomicAdd(&cnt[dst[e]], 1);
}

__global__ __launch_bounds__(256) void dinv_k(const int* __restrict__ cnt, float* __restrict__ dinv) {
  int i = blockIdx.x * 256 + threadIdx.x;
  if (i < NN) dinv[i] = rsqrtf((float)cnt[i]); // cnt already includes self-loop
}

__global__ __launch_bounds__(1024) void scan_k(const int* __restrict__ cnt, int* __restrict__ rowp,
                                               int* __restrict__ cursor) {
  __shared__ int sums[1024];
  const int t = threadIdx.x;
  const int chunk = (NN + 1023) / 1024;      // 49
  const int beg = t * chunk;
  const int end = (beg + chunk < NN) ? (beg + chunk) : NN;
  int s = 0;
  for (int i = beg; i < end; ++i) s += cnt[i];
  sums[t] = s;
  __syncthreads();
  for (int off = 1; off < 1024; off <<= 1) {   // inclusive Hillis-Steele
    int v = sums[t];
    int u = (t >= off) ? sums[t - off] : 0;
    __syncthreads();
    sums[t] = v + u;
    __syncthreads();
  }
  int run = (t == 0) ? 0 : sums[t - 1];
  for (int i = beg; i < end; ++i) { rowp[i] = run; cursor[i] = run; run += cnt[i]; }
  if (t == 1023) rowp[NN] = run;               // chunks past NN are empty -> run == total
}

// csr entry: .x = src node, .y = weight bits
__global__ __launch_bounds__(256) void scatter_k(const int* __restrict__ src, const int* __restrict__ dst,
                                                 const float* __restrict__ dinv, int* __restrict__ cursor,
                                                 int2* __restrict__ csr) {
  int e = blockIdx.x * 256 + threadIdx.x;
  if (e < EE) {
    int d = dst[e], s = src[e];
    int pos = atomicAdd(&cursor[d], 1);
    csr[pos] = make_int2(s, __float_as_int(dinv[s] * dinv[d]));
  } else if (e < EE + NN) {
    int i = e - EE;                            // self-loop edge
    int pos = atomicAdd(&cursor[i], 1);
    float di = dinv[i];
    csr[pos] = make_int2(i, __float_as_int(di * di));
  }
}

// ---------------- dtype conversion ----------------

__global__ __launch_bounds__(256) void convert_x_k(const float* __restrict__ x, u16* __restrict__ xb) {
  size_t i = ((size_t)blockIdx.x * 256 + threadIdx.x) * 4;
  if (i >= (size_t)MP * DD) return;
  s16x4 v;
  if (i < (size_t)NN * DD) {
    f32x4 f = *(const f32x4*)(x + i);
    v = (s16x4){ (short)f2bf(f.x), (short)f2bf(f.y), (short)f2bf(f.z), (short)f2bf(f.w) };
  } else {
    v = (s16x4){ 0, 0, 0, 0 };                 // zero pad rows (M -> MP)
  }
  *(s16x4*)(xb + i) = v;
}

__global__ __launch_bounds__(256) void convert_wt_k(const float* __restrict__ W, u16* __restrict__ WT, int ncols) {
  int idx = blockIdx.x * 256 + threadIdx.x;    // over ncols*512, WT is [ncols][512] = B^T
  if (idx >= 512 * ncols) return;
  int n = idx >> 9, k = idx & 511;
  WT[idx] = f2bf(W[(size_t)k * ncols + n]);
}

// ---------------- bf16 MFMA GEMM (m97 structure: 128x128 tile, 4 waves, BK=32) ----------------

template<int OUT_BF16>
__global__ __launch_bounds__(256) void gemm_k(const u16* __restrict__ A, const u16* __restrict__ BT,
                                              void* __restrict__ Cv, const float* __restrict__ bias,
                                              int M, int N) {
  __shared__ u16 As[128 * 32];
  __shared__ u16 Bs[128 * 32];
  const int ntn = N >> 7;
  const int bm = (int)blockIdx.x / ntn;
  const int bn = (int)blockIdx.x % ntn;
  const int t = threadIdx.x;
  const int lane = t & 63;
  const int wc = (t >> 6) & 1;
  const int wr = (t >> 7) & 1;
  f32x4 acc[4][4] = {};
  const int r0 = t >> 2;                        // staging row 0..63
  const int kc = (t & 3) * 8;                   // staging k-col
  const u16* Ab = A + (size_t)bm * 128 * DD + (size_t)r0 * DD + kc;
  const u16* Bb = BT + (size_t)bn * 128 * DD + (size_t)r0 * DD + kc;

  for (int kt = 0; kt < DD; kt += 32) {
    __builtin_amdgcn_global_load_lds((GVoid*)(Ab + kt),           (LVoid*)(&As[t * 8]),        16, 0, 0);
    __builtin_amdgcn_global_load_lds((GVoid*)(Ab + 64 * DD + kt), (LVoid*)(&As[2048 + t * 8]), 16, 0, 0);
    __builtin_amdgcn_global_load_lds((GVoid*)(Bb + kt),           (LVoid*)(&Bs[t * 8]),        16, 0, 0);
    __builtin_amdgcn_global_load_lds((GVoid*)(Bb + 64 * DD + kt), (LVoid*)(&Bs[2048 + t * 8]), 16, 0, 0);
    __syncthreads();                            // compiler drains vmcnt before barrier
    bf16x8 af[4], bv[4];
    #pragma unroll
    for (int m = 0; m < 4; ++m)
      af[m] = *(const bf16x8*)&As[(wr * 64 + m * 16 + (lane & 15)) * 32 + (lane >> 4) * 8];
    #pragma unroll
    for (int n = 0; n < 4; ++n)
      bv[n] = *(const bf16x8*)&Bs[(wc * 64 + n * 16 + (lane & 15)) * 32 + (lane >> 4) * 8];
    #pragma unroll
    for (int m = 0; m < 4; ++m) {
      #pragma unroll
      for (int n = 0; n < 4; ++n)
        acc[m][n] = __builtin_amdgcn_mfma_f32_16x16x32_bf16(af[m], bv[n], acc[m][n], 0, 0, 0);
    }
    __syncthreads();                            // protect LDS before next stage
  }

  // C layout (m89-verified): col = lane&15, row = (lane>>4)*4 + reg
  const int rb = bm * 128 + wr * 64 + ((lane >> 4) * 4);
  const int cb = bn * 128 + wc * 64 + (lane & 15);
  #pragma unroll
  for (int m = 0; m < 4; ++m) {
    #pragma unroll
    for (int r = 0; r < 4; ++r) {
      const int row = rb + m * 16 + r;
      if (row < M) {
        #pragma unroll
        for (int n = 0; n < 4; ++n) {
          const int col = cb + n * 16;
          float v = acc[m][n][r];
          if (bias) v += bias[col];
          if (OUT_BF16) ((u16*)Cv)[(size_t)row * N + col] = f2bf(v);
          else          ((float*)Cv)[(size_t)row * N + col] = v;
        }
      }
    }
  }
}

// ---------------- CSR aggregation: wave per node, 4-edge-deep pipeline ----------------
// 4 gathers (4 KB) in flight per wave before any FMA -> hide HBM/L3 miss latency.

__global__ __launch_bounds__(256) void aggregate_k(const u16* __restrict__ H, const int* __restrict__ rowp,
                                                   const int2* __restrict__ csr,
                                                   const float* __restrict__ bias,
                                                   u16* __restrict__ out) {
  const int wid = threadIdx.x >> 6;
  const int lane = threadIdx.x & 63;
  const int node = blockIdx.x * 4 + wid;        // grid = NN/4 exactly
  const int d0 = lane * 8;
  const int beg = rowp[node];
  const int end = rowp[node + 1];
  float acc[8] = {0.f, 0.f, 0.f, 0.f, 0.f, 0.f, 0.f, 0.f};
  int e = beg;
  for (; e + 4 <= end; e += 4) {
    const int2 c0 = csr[e], c1 = csr[e + 1], c2 = csr[e + 2], c3 = csr[e + 3];
    const s16x8 v0 = *(const s16x8*)(H + (size_t)c0.x * DD + d0);
    const s16x8 v1 = *(const s16x8*)(H + (size_t)c1.x * DD + d0);
    const s16x8 v2 = *(const s16x8*)(H + (size_t)c2.x * DD + d0);
    const s16x8 v3 = *(const s16x8*)(H + (size_t)c3.x * DD + d0);
    const float w0 = __int_as_float(c0.y), w1 = __int_as_float(c1.y);
    const float w2 = __int_as_float(c2.y), w3 = __int_as_float(c3.y);
    #pragma unroll
    for (int j = 0; j < 8; ++j) {
      acc[j] += bf2f((u16)v0[j]) * w0;
      acc[j] += bf2f((u16)v1[j]) * w1;
      acc[j] += bf2f((u16)v2[j]) * w2;
      acc[j] += bf2f((u16)v3[j]) * w3;
    }
  }
  for (; e < end; ++e) {
    const int2 c = csr[e];
    const s16x8 v = *(const s16x8*)(H + (size_t)c.x * DD + d0);
    const float w = __int_as_float(c.y);
    #pragma unroll
    for (int j = 0; j < 8; ++j) acc[j] += bf2f((u16)v[j]) * w;
  }
  s16x8 o;
  #pragma unroll
  for (int j = 0; j < 8; ++j) {
    float r = acc[j] + bias[d0 + j];
    r = fmaxf(r, 0.f);                          // relu
    o[j] = (short)f2bf(r);
  }
  *(s16x8*)(out + (size_t)node * DD + d0) = o;
}

// ---------------- launch ----------------

extern "C" void kernel_launch(void* const* d_in, const int* in_sizes, int n_in,
                              void* d_out, int out_size, void* d_ws, size_t ws_size,
                              hipStream_t stream) {
  const float* x    = (const float*)d_in[0];
  const int*   ei   = (const int*)d_in[1];
  const float* W1   = (const float*)d_in[2];
  const float* b1   = (const float*)d_in[3];
  const float* W2   = (const float*)d_in[4];
  const float* b2   = (const float*)d_in[5];
  const float* Wout = (const float*)d_in[6];
  const float* bout = (const float*)d_in[7];
  float* out = (float*)d_out;
  (void)in_sizes; (void)n_in; (void)out_size; (void)ws_size;

  char* ws = (char*)d_ws;
  size_t off = 0;
  auto alloc = [&](size_t bytes) -> char* {
    char* p = ws + off;
    off = (off + bytes + 255) & ~(size_t)255;
    return p;
  };
  u16*   xb   = (u16*)alloc((size_t)MP * DD * 2);   // activations bf16, padded rows
  u16*   H    = (u16*)alloc((size_t)NN * DD * 2);   // GEMM output bf16
  u16*   W1T  = (u16*)alloc(512 * 512 * 2);
  u16*   W2T  = (u16*)alloc(512 * 512 * 2);
  u16*   WoT  = (u16*)alloc(256 * 512 * 2);
  int*   cnt  = (int*)alloc(NN * 4);
  float* dinv = (float*)alloc(NN * 4);
  int*   rowp = (int*)alloc((NN + 1) * 4);
  int*   cur  = (int*)alloc(NN * 4);
  int2*  csr  = (int2*)alloc((size_t)(EE + NN) * 8);

  const int* srcp = ei;        // edge_index[0]
  const int* dstp = ei + EE;   // edge_index[1]

  init_cnt_k<<<(NN + 255) / 256, 256, 0, stream>>>(cnt);
  count_k<<<(EE + 255) / 256, 256, 0, stream>>>(dstp, cnt);
  dinv_k<<<(NN + 255) / 256, 256, 0, stream>>>(cnt, dinv);
  scan_k<<<1, 1024, 0, stream>>>(cnt, rowp, cur);
  scatter_k<<<(EE + NN + 255) / 256, 256, 0, stream>>>(srcp, dstp, dinv, cur, csr);
  convert_x_k<<<(int)(((size_t)MP * DD / 4 + 255) / 256), 256, 0, stream>>>(x, xb);
  convert_wt_k<<<(512 * 512 + 255) / 256, 256, 0, stream>>>(W1, W1T, 512);
  convert_wt_k<<<(512 * 512 + 255) / 256, 256, 0, stream>>>(W2, W2T, 512);
  convert_wt_k<<<(512 * 256 + 255) / 256, 256, 0, stream>>>(Wout, WoT, 256);

  // layer 1: H = xb @ W1 ; xb = relu(agg(H) + b1)
  gemm_k<1><<<(MP / 128) * (512 / 128), 256, 0, stream>>>(xb, W1T, (void*)H, nullptr, NN, 512);
  aggregate_k<<<NN / 4, 256, 0, stream>>>(H, rowp, csr, b1, xb);
  // layer 2
  gemm_k<1><<<(MP / 128) * (512 / 128), 256, 0, stream>>>(xb, W2T, (void*)H, nullptr, NN, 512);
  aggregate_k<<<NN / 4, 256, 0, stream>>>(H, rowp, csr, b2, xb);
  // output layer: out = xb @ Wout + bout (f32, no relu, no aggregation)
  gemm_k<0><<<(MP / 128) * (256 / 128), 256, 0, stream>>>(xb, WoT, (void*)out, bout, NN, 256);
}